// Round 4
// baseline (36165.509 us; speedup 1.0000x reference)
//
#include <hip/hip_runtime.h>
#include <math.h>

#define LSTR 36  // LDS row stride in floats (144B: 16B-aligned, conflict-benign)

// ===========================================================================
// Phase 0/2 GEMM (unchanged from round 1: register-staged double-buffered)
// ===========================================================================
__device__ __forceinline__ void gemm_core(
    const float* __restrict__ A, int lda,
    const float* __restrict__ W, int ldw,
    int n0, int N, int K,
    const float* __restrict__ b1, const float* __restrict__ b2,
    int act, float* __restrict__ C, int ldc, int row0,
    float* As, float* Ws)
{
    const int tid = threadIdx.x;
    const int jl = tid & 15;
    const int bg = tid >> 4;
    float acc[4][4] = {{0.f,0.f,0.f,0.f},{0.f,0.f,0.f,0.f},{0.f,0.f,0.f,0.f},{0.f,0.f,0.f,0.f}};

    float4 ra[2], rw[4];
    int ar[2], akv[2], wr[4], wkv[4];
#pragma unroll
    for (int p = 0; p < 2; ++p) {
        int i = tid + 128 * p;
        ar[p] = i >> 3; akv[p] = (i & 7) << 2;
    }
#pragma unroll
    for (int p = 0; p < 4; ++p) {
        int i = tid + 128 * p;
        wr[p] = i >> 3; wkv[p] = (i & 7) << 2;
    }

#pragma unroll
    for (int p = 0; p < 2; ++p)
        ra[p] = *(const float4*)(A + (size_t)(row0 + ar[p]) * lda + akv[p]);
#pragma unroll
    for (int p = 0; p < 4; ++p) {
        int n = n0 + wr[p];
        rw[p] = (n < N) ? *(const float4*)(W + (size_t)n * ldw + wkv[p])
                        : make_float4(0.f, 0.f, 0.f, 0.f);
    }

    for (int kk = 0; kk < K; kk += 32) {
#pragma unroll
        for (int p = 0; p < 2; ++p)
            *(float4*)&As[ar[p] * LSTR + akv[p]] = ra[p];
#pragma unroll
        for (int p = 0; p < 4; ++p)
            *(float4*)&Ws[wr[p] * LSTR + wkv[p]] = rw[p];
        __syncthreads();

        if (kk + 32 < K) {
            int kn = kk + 32;
#pragma unroll
            for (int p = 0; p < 2; ++p)
                ra[p] = *(const float4*)(A + (size_t)(row0 + ar[p]) * lda + kn + akv[p]);
#pragma unroll
            for (int p = 0; p < 4; ++p) {
                int n = n0 + wr[p];
                rw[p] = (n < N) ? *(const float4*)(W + (size_t)n * ldw + kn + wkv[p])
                                : make_float4(0.f, 0.f, 0.f, 0.f);
            }
        }

#pragma unroll
        for (int k4 = 0; k4 < 8; ++k4) {
            float4 av[4], wv[4];
#pragma unroll
            for (int jb = 0; jb < 4; ++jb) av[jb] = *(float4*)&As[(bg + 8 * jb) * LSTR + k4 * 4];
#pragma unroll
            for (int jn = 0; jn < 4; ++jn) wv[jn] = *(float4*)&Ws[(jl + 16 * jn) * LSTR + k4 * 4];
#pragma unroll
            for (int jn = 0; jn < 4; ++jn)
#pragma unroll
                for (int jb = 0; jb < 4; ++jb) {
                    acc[jn][jb] += av[jb].x * wv[jn].x;
                    acc[jn][jb] += av[jb].y * wv[jn].y;
                    acc[jn][jb] += av[jb].z * wv[jn].z;
                    acc[jn][jb] += av[jb].w * wv[jn].w;
                }
        }
        __syncthreads();
    }

#pragma unroll
    for (int jn = 0; jn < 4; ++jn) {
        int n = n0 + jl + 16 * jn;
        if (n < N) {
            float bb = (b1 ? b1[n] : 0.f) + (b2 ? b2[n] : 0.f);
#pragma unroll
            for (int jb = 0; jb < 4; ++jb) {
                int b = bg + 8 * jb;
                float x = acc[jn][jb] + bb;
                if (act == 1) x = tanhf(x);
                C[(size_t)(row0 + b) * ldc + n] = x;
            }
        }
    }
}

__global__ void __launch_bounds__(128) gemm_generic(
    const float* __restrict__ A, int lda, const float* __restrict__ W, int ldw,
    const float* __restrict__ b1, const float* __restrict__ b2,
    float* __restrict__ C, int ldc, int N, int K, int act, int swapxy)
{
    __shared__ __align__(16) float As[32 * LSTR];
    __shared__ __align__(16) float Ws[64 * LSTR];
    int bn = swapxy ? blockIdx.y : blockIdx.x;
    int bm = swapxy ? blockIdx.x : blockIdx.y;
    gemm_core(A, lda, W, ldw, bn * 64, N, K, b1, b2, act, C, ldc, bm * 32, As, Ws);
}

// ===========================================================================
// Register-resident persistent recurrence.
// 248 blocks x 256 threads (1/CU). Each block-group holds ONE weight matrix
// in VGPRs for all 64 timesteps: thread = 4 rows x 64-K-slice = 256 floats.
// Only the small state vectors cross blocks, via per-(t,stage) flag counters.
// Layout per block: lane l: ks = l % KS (K-slice), rg = l / KS (row group).
// Reduction over K-slices: in-wave shfl_xor butterfly (KS = 16 or 4 lanes).
// h staged to LDS per 8-batch chunk, T14 register prefetch, stride-68 pad
// (2-way bank aliasing = free per m136).
// ===========================================================================

// flag ids within a step
#define FU   0
#define FPHP 1
#define FB   2
#define FV   3
#define FW0  4
#define FD   5
#define FW1  6
#define FE   7

__device__ __forceinline__ void flag_set(unsigned* F, int idx)
{
    __syncthreads();                    // all block writes issued+drained (barrier waits vmcnt)
    if (threadIdx.x == 0) {
        __threadfence();                // release to coherence point
        __hip_atomic_fetch_add(&F[idx], 1u, __ATOMIC_RELEASE,
                               __HIP_MEMORY_SCOPE_AGENT);
    }
}

__device__ __forceinline__ void flag_wait(unsigned* F, int idx, unsigned need)
{
    if (threadIdx.x == 0) {
        while (__hip_atomic_load(&F[idx], __ATOMIC_RELAXED,
                                 __HIP_MEMORY_SCOPE_AGENT) < need)
            __builtin_amdgcn_s_sleep(2);
        __threadfence();                // acquire: see producer's data
    }
    __syncthreads();
}

// load this thread's 4 weight rows (64-float K-slice each) into registers
template<int KS>
__device__ __forceinline__ void rr_load_w(
    float4 (&Wv)[4][16], const float* __restrict__ W, int ldw, int kofs,
    int r0, int r1, int r2, int r3)
{
    const int l  = threadIdx.x & 63;
    const int ks = l % KS;
    const int k0 = kofs + ks * 64;
    const float* p0 = W + (size_t)r0 * ldw + k0;
    const float* p1 = W + (size_t)r1 * ldw + k0;
    const float* p2 = W + (size_t)r2 * ldw + k0;
    const float* p3 = W + (size_t)r3 * ldw + k0;
#pragma unroll
    for (int f4 = 0; f4 < 16; ++f4) {
        Wv[0][f4] = *(const float4*)(p0 + f4 * 4);
        Wv[1][f4] = *(const float4*)(p1 + f4 * 4);
        Wv[2][f4] = *(const float4*)(p2 + f4 * 4);
        Wv[3][f4] = *(const float4*)(p3 + f4 * 4);
    }
}

// MODE 0: C[b][nbase+m] = act(acc + bias[m]);  MODE 1: LSTM cell for hidden j
template<int KS, int MODE>
__device__ __forceinline__ void rr_core(
    float4 (&Wv)[4][16],
    const float* __restrict__ hsrc,     // [32][K] b-major
    float* __restrict__ hl,             // LDS: 8*KS*68 floats
    int c0, int c1,
    float* __restrict__ Cout, int ldc, int nbase, float4 bias, int act,
    int j, int H,
    const float* __restrict__ addA, int ldA,
    const float* __restrict__ addB, int ldB,
    float* __restrict__ h_out, float* __restrict__ c_st)
{
    const int tid = threadIdx.x;
    const int l   = tid & 63;
    const int ks  = l % KS;
    const int K   = KS * 64;
    const int F4B = K / 4;              // float4 per batch row
    const int NF4 = K / 128;            // staged float4 per thread (8 or 2)

    float4 st[NF4];
    // prefetch chunk c0
#pragma unroll
    for (int p = 0; p < NF4; ++p) {
        int i  = tid + 256 * p;
        int bl = i / F4B;
        int kk = (i % F4B) * 4;
        st[p] = *(const float4*)(hsrc + (size_t)(c0 * 8 + bl) * K + kk);
    }

    for (int c = c0; c < c1; ++c) {
        // write staged regs -> LDS
#pragma unroll
        for (int p = 0; p < NF4; ++p) {
            int i  = tid + 256 * p;
            int bl = i / F4B;
            int kk = (i % F4B) * 4;
            *(float4*)&hl[(bl * KS + (kk >> 6)) * 68 + (kk & 63)] = st[p];
        }
        __syncthreads();
        // prefetch next chunk (hides L3 latency under compute)
        if (c + 1 < c1) {
#pragma unroll
            for (int p = 0; p < NF4; ++p) {
                int i  = tid + 256 * p;
                int bl = i / F4B;
                int kk = (i % F4B) * 4;
                st[p] = *(const float4*)(hsrc + (size_t)((c + 1) * 8 + bl) * K + kk);
            }
        }

        float acc[4][8];
#pragma unroll
        for (int m = 0; m < 4; ++m)
#pragma unroll
            for (int bl = 0; bl < 8; ++bl) acc[m][bl] = 0.f;

#pragma unroll
        for (int bl = 0; bl < 8; ++bl)
#pragma unroll
            for (int f4 = 0; f4 < 16; ++f4) {
                float4 hv = *(float4*)&hl[(bl * KS + ks) * 68 + f4 * 4];
#pragma unroll
                for (int m = 0; m < 4; ++m) {
                    acc[m][bl] += Wv[m][f4].x * hv.x;
                    acc[m][bl] += Wv[m][f4].y * hv.y;
                    acc[m][bl] += Wv[m][f4].z * hv.z;
                    acc[m][bl] += Wv[m][f4].w * hv.w;
                }
            }
        __syncthreads();   // LDS free for next chunk / next call

        // butterfly reduce across the KS k-slice lanes
#pragma unroll
        for (int off = KS / 2; off >= 1; off >>= 1)
#pragma unroll
            for (int m = 0; m < 4; ++m)
#pragma unroll
                for (int bl = 0; bl < 8; ++bl)
                    acc[m][bl] += __shfl_xor(acc[m][bl], off);

        // write outputs: lane with (bl % KS) == ks owns batch-local bl
#pragma unroll
        for (int bl = 0; bl < 8; ++bl) {
            if ((bl % KS) == ks) {
                int b = c * 8 + bl;
                if (MODE == 0) {
                    float r0 = acc[0][bl] + bias.x;
                    float r1 = acc[1][bl] + bias.y;
                    float r2 = acc[2][bl] + bias.z;
                    float r3 = acc[3][bl] + bias.w;
                    if (act) { r0 = tanhf(r0); r1 = tanhf(r1); r2 = tanhf(r2); r3 = tanhf(r3); }
                    float4 o = make_float4(r0, r1, r2, r3);
                    *(float4*)&Cout[(size_t)b * ldc + nbase] = o;
                } else {
                    float g[4];
#pragma unroll
                    for (int m = 0; m < 4; ++m) {
                        float x = acc[m][bl];
                        if (addA) x += addA[(size_t)b * ldA + m * H + j];
                        if (addB) x += addB[(size_t)b * ldB + m * H + j];
                        g[m] = x;
                    }
                    float co = c_st[(size_t)b * H + j];
                    float ii = 1.f / (1.f + expf(-g[0]));
                    float ff = 1.f / (1.f + expf(-g[1]));
                    float gg = tanhf(g[2]);
                    float oo = 1.f / (1.f + expf(-g[3]));
                    float cn = ff * co + ii * gg;
                    float hn = oo * tanhf(cn);
                    c_st[(size_t)b * H + j] = cn;
                    h_out[(size_t)b * H + j] = hn;
                }
            }
        }
    }
}

struct RecArgs {
    const float *w2p_W, *w2p_b, *p_Whh0, *p2w_W, *p2w_b;
    const float *p_Wih0, *w_Wih0, *w_Wih1;
    const float *w_Whh0, *w_Whh1, *w_bih1, *w_bhh1;
    const float *Ap, *Aw;
    float *u, *v, *hp_hh, *w0_hh, *w1_hh;
    float *Hp, *Hw1, *h_w0, *c_p, *c_w0, *c_w1;
    unsigned *flags;
};

// group map:
//   0..63   G_W1HH : w1_hh = w_Whh1 @ hw1(t-1) + bih1+bhh1        [wait E(t-1)]
//  64..127  G_W0HH : w0_hh = w_Whh0 @ h_w0(t-1)                   [wait D(t-1)]
// 128..143  G_U    : u = tanh(w2p @ hw1(t-1) + b)                 [wait E(t-1)]
// 144..147  G_PHP  : hp_hh = p_Whh0 @ h_p(t-1)                    [wait B(t-1)]
// 148..163  G_P    : p-LSTM -> Hp(t), c_p                         [wait U,PHP]
// 164..167  G_V    : v = tanh(p2w @ h_p(t) + b)  (chunk-split)    [wait B]
// 168..183  G_WL0  : w-LSTM0 -> h_w0, c_w0                        [wait V,W0HH]
// 184..247  G_WL1  : w-LSTM1 -> Hw1(t), c_w1                      [wait D,W1HH]
__global__ void __launch_bounds__(256, 1) recurrence_rr(RecArgs a)
{
    __shared__ __align__(16) float hl[8 * 16 * 68];
    const int blk = blockIdx.x;
    const int tid = threadIdx.x;
    const int l = tid & 63, w = tid >> 6;
    unsigned* F = a.flags;

    if (blk < 64) {                                   // G_W1HH  KS=16 GEMM
        const int rg = l / 16;
        const int nb = blk * 64 + w * 16 + rg * 4;
        float4 Wv[4][16];
        rr_load_w<16>(Wv, a.w_Whh1, 1024, 0, nb, nb + 1, nb + 2, nb + 3);
        float4 bias = make_float4(
            a.w_bih1[nb] + a.w_bhh1[nb], a.w_bih1[nb+1] + a.w_bhh1[nb+1],
            a.w_bih1[nb+2] + a.w_bhh1[nb+2], a.w_bih1[nb+3] + a.w_bhh1[nb+3]);
        for (int t = 0; t < 64; ++t) {
            if (t) flag_wait(F, (t-1)*8 + FE, 64);
            rr_core<16,0>(Wv, a.Hw1 + (size_t)t*32*1024, hl, 0, 4,
                          a.w1_hh, 4096, nb, bias, 0,
                          0, 0, nullptr, 0, nullptr, 0, nullptr, nullptr);
            flag_set(F, t*8 + FW1);
        }
    } else if (blk < 128) {                           // G_W0HH  KS=16 GEMM
        const int rg = l / 16;
        const int nb = (blk - 64) * 64 + w * 16 + rg * 4;
        float4 Wv[4][16];
        rr_load_w<16>(Wv, a.w_Whh0, 1024, 0, nb, nb + 1, nb + 2, nb + 3);
        float4 bias = make_float4(0.f, 0.f, 0.f, 0.f);
        for (int t = 0; t < 64; ++t) {
            if (t) flag_wait(F, (t-1)*8 + FD, 16);
            rr_core<16,0>(Wv, a.h_w0, hl, 0, 4,
                          a.w0_hh, 4096, nb, bias, 0,
                          0, 0, nullptr, 0, nullptr, 0, nullptr, nullptr);
            flag_set(F, t*8 + FW0);
        }
    } else if (blk < 144) {                           // G_U  KS=16 GEMM tanh
        const int rg = l / 16;
        const int nb = (blk - 128) * 64 + w * 16 + rg * 4;
        float4 Wv[4][16];
        rr_load_w<16>(Wv, a.w2p_W, 1024, 0, nb, nb + 1, nb + 2, nb + 3);
        float4 bias = make_float4(a.w2p_b[nb], a.w2p_b[nb+1], a.w2p_b[nb+2], a.w2p_b[nb+3]);
        for (int t = 0; t < 64; ++t) {
            if (t) flag_wait(F, (t-1)*8 + FE, 64);
            rr_core<16,0>(Wv, a.Hw1 + (size_t)t*32*1024, hl, 0, 4,
                          a.u, 1024, nb, bias, 1,
                          0, 0, nullptr, 0, nullptr, 0, nullptr, nullptr);
            flag_set(F, t*8 + FU);
        }
    } else if (blk < 148) {                           // G_PHP  KS=4 GEMM
        const int rg = l / 4;
        const int nb = (blk - 144) * 256 + w * 64 + rg * 4;
        float4 Wv[4][16];
        rr_load_w<4>(Wv, a.p_Whh0, 256, 0, nb, nb + 1, nb + 2, nb + 3);
        float4 bias = make_float4(0.f, 0.f, 0.f, 0.f);
        for (int t = 0; t < 64; ++t) {
            if (t) flag_wait(F, (t-1)*8 + FB, 16);
            rr_core<4,0>(Wv, a.Hp + (size_t)t*32*256, hl, 0, 4,
                         a.hp_hh, 1024, nb, bias, 0,
                         0, 0, nullptr, 0, nullptr, 0, nullptr, nullptr);
            flag_set(F, t*8 + FPHP);
        }
    } else if (blk < 164) {                           // G_P  KS=16 LSTM H=256
        const int rg = l / 16;
        const int j = (blk - 148) * 16 + w * 4 + rg;
        float4 Wv[4][16];
        rr_load_w<16>(Wv, a.p_Wih0, 1152, 128, j, 256 + j, 512 + j, 768 + j);
        float4 bias = make_float4(0.f, 0.f, 0.f, 0.f);
        for (int t = 0; t < 64; ++t) {
            flag_wait(F, t*8 + FU, 16);
            flag_wait(F, t*8 + FPHP, 4);
            rr_core<16,1>(Wv, a.u, hl, 0, 4,
                          nullptr, 0, 0, bias, 0,
                          j, 256, a.Ap + (size_t)t*32*1024, 1024, a.hp_hh, 1024,
                          a.Hp + (size_t)(t+1)*32*256, a.c_p);
            flag_set(F, t*8 + FB);
        }
    } else if (blk < 168) {                           // G_V  KS=4 GEMM tanh, chunk-split
        const int rg = l / 4;
        const int nb = w * 64 + rg * 4;
        const int c0 = blk - 164;
        float4 Wv[4][16];
        rr_load_w<4>(Wv, a.p2w_W, 256, 0, nb, nb + 1, nb + 2, nb + 3);
        float4 bias = make_float4(a.p2w_b[nb], a.p2w_b[nb+1], a.p2w_b[nb+2], a.p2w_b[nb+3]);
        for (int t = 0; t < 64; ++t) {
            flag_wait(F, t*8 + FB, 16);
            rr_core<4,0>(Wv, a.Hp + (size_t)(t+1)*32*256, hl, c0, c0 + 1,
                         a.v, 256, nb, bias, 1,
                         0, 0, nullptr, 0, nullptr, 0, nullptr, nullptr);
            flag_set(F, t*8 + FV);
        }
    } else if (blk < 184) {                           // G_WL0  KS=4 LSTM H=1024
        const int rg = l / 4;
        const int j = (blk - 168) * 64 + w * 16 + rg;
        float4 Wv[4][16];
        rr_load_w<4>(Wv, a.w_Wih0, 768, 512, j, 1024 + j, 2048 + j, 3072 + j);
        float4 bias = make_float4(0.f, 0.f, 0.f, 0.f);
        for (int t = 0; t < 64; ++t) {
            flag_wait(F, t*8 + FV, 4);
            flag_wait(F, t*8 + FW0, 64);
            rr_core<4,1>(Wv, a.v, hl, 0, 4,
                         nullptr, 0, 0, bias, 0,
                         j, 1024, a.Aw + (size_t)t*32*4096, 4096, a.w0_hh, 4096,
                         a.h_w0, a.c_w0);
            flag_set(F, t*8 + FD);
        }
    } else {                                          // G_WL1  KS=16 LSTM H=1024
        const int rg = l / 16;
        const int j = (blk - 184) * 16 + w * 4 + rg;
        float4 Wv[4][16];
        rr_load_w<16>(Wv, a.w_Wih1, 1024, 0, j, 1024 + j, 2048 + j, 3072 + j);
        float4 bias = make_float4(0.f, 0.f, 0.f, 0.f);
        for (int t = 0; t < 64; ++t) {
            flag_wait(F, t*8 + FD, 16);
            flag_wait(F, t*8 + FW1, 64);
            rr_core<16,1>(Wv, a.h_w0, hl, 0, 4,
                          nullptr, 0, 0, bias, 0,
                          j, 1024, nullptr, 0, a.w1_hh, 4096,
                          a.Hw1 + (size_t)(t+1)*32*1024, a.c_w1);
            flag_set(F, t*8 + FE);
        }
    }
}

// ===========================================================================
// Embedding gather / heads (unchanged)
// ===========================================================================
__global__ void __launch_bounds__(128) gather_emb(
    const int* __restrict__ pos, const int* __restrict__ word,
    const float* __restrict__ pe, const float* __restrict__ we,
    float* __restrict__ Xp, float* __restrict__ Xw)
{
    int row = blockIdx.x;
    int p = pos[row];
    int w = word[row];
    for (int i = threadIdx.x; i < 128; i += 128)
        Xp[(size_t)row * 128 + i] = pe[(size_t)p * 128 + i];
    for (int i = threadIdx.x; i < 512; i += 128)
        Xw[(size_t)row * 512 + i] = we[(size_t)w * 512 + i];
}

__global__ void __launch_bounds__(256) pos_out_k(
    const float* __restrict__ Hp, const float* __restrict__ W,
    const float* __restrict__ bias, float* __restrict__ out)
{
    int row = blockIdx.x * 4 + (threadIdx.x >> 6);
    int lane = threadIdx.x & 63;
    const float* h = Hp + (size_t)row * 256;
    float logit = -INFINITY;
    if (lane < 48) {
        float s = bias[lane];
        const float* w = W + (size_t)lane * 256;
        for (int k = 0; k < 256; k += 4) {
            s += h[k] * w[k];
            s += h[k + 1] * w[k + 1];
            s += h[k + 2] * w[k + 2];
            s += h[k + 3] * w[k + 3];
        }
        logit = s;
    }
    float m = logit;
    for (int off = 1; off < 64; off <<= 1) m = fmaxf(m, __shfl_xor(m, off));
    float e = (lane < 48) ? expf(logit - m) : 0.f;
    float ssum = e;
    for (int off = 1; off < 64; off <<= 1) ssum += __shfl_xor(ssum, off);
    float ls = m + logf(ssum);
    if (lane < 48) out[(size_t)row * 48 + lane] = logit - ls;
}

__global__ void __launch_bounds__(256) logsoftmax_w(float* __restrict__ out)
{
    __shared__ float redm[256], reds[256];
    int row = blockIdx.x;
    float* p = out + (size_t)row * 32000;
    float4* p4 = (float4*)p;
    int tid = threadIdx.x;

    float m = -INFINITY, s = 0.f;
    for (int i = tid; i < 8000; i += 256) {
        float4 v = p4[i];
        float x;
        x = v.x; if (x > m) { s = s * expf(m - x) + 1.f; m = x; } else s += expf(x - m);
        x = v.y; if (x > m) { s = s * expf(m - x) + 1.f; m = x; } else s += expf(x - m);
        x = v.z; if (x > m) { s = s * expf(m - x) + 1.f; m = x; } else s += expf(x - m);
        x = v.w; if (x > m) { s = s * expf(m - x) + 1.f; m = x; } else s += expf(x - m);
    }
    redm[tid] = m; reds[tid] = s;
    __syncthreads();
    for (int st = 128; st > 0; st >>= 1) {
        if (tid < st) {
            float m2 = redm[tid + st], s2 = reds[tid + st];
            float M = fmaxf(redm[tid], m2);
            reds[tid] = reds[tid] * expf(redm[tid] - M) + s2 * expf(m2 - M);
            redm[tid] = M;
        }
        __syncthreads();
    }
    float ls = redm[0] + logf(reds[0]);

    for (int i = tid; i < 8000; i += 256) {
        float4 v = p4[i];
        v.x -= ls; v.y -= ls; v.z -= ls; v.w -= ls;
        p4[i] = v;
    }
}

// ===========================================================================
extern "C" void kernel_launch(void* const* d_in, const int* in_sizes, int n_in,
                              void* d_out, int out_size, void* d_ws, size_t ws_size,
                              hipStream_t stream)
{
    const int T = 64, B = 32, TB = T * B;  // 2048

    const int*   pos         = (const int*)d_in[0];
    const int*   word        = (const int*)d_in[1];
    const float* pos_emb_W   = (const float*)d_in[2];
    const float* word_emb_W  = (const float*)d_in[3];
    const float* w2p_W       = (const float*)d_in[4];
    const float* w2p_b       = (const float*)d_in[5];
    const float* p2w_W       = (const float*)d_in[6];
    const float* p2w_b       = (const float*)d_in[7];
    const float* p_Wih0      = (const float*)d_in[8];
    const float* p_Whh0      = (const float*)d_in[9];
    const float* p_bih0      = (const float*)d_in[10];
    const float* p_bhh0      = (const float*)d_in[11];
    const float* w_Wih0      = (const float*)d_in[12];
    const float* w_Whh0      = (const float*)d_in[13];
    const float* w_bih0      = (const float*)d_in[14];
    const float* w_bhh0      = (const float*)d_in[15];
    const float* w_Wih1      = (const float*)d_in[16];
    const float* w_Whh1      = (const float*)d_in[17];
    const float* w_bih1      = (const float*)d_in[18];
    const float* w_bhh1      = (const float*)d_in[19];
    const float* pos_proj_W  = (const float*)d_in[20];
    const float* pos_proj_b  = (const float*)d_in[21];
    const float* word_proj1W = (const float*)d_in[22];
    const float* word_proj1b = (const float*)d_in[23];
    const float* word_proj2b = (const float*)d_in[24];

    float* out   = (float*)d_out;
    float* Pout  = out;                 // [2048 x 48]
    float* Wout  = out + (size_t)TB * 48;  // [2048 x 32000]

    // workspace layout (floats)
    float* ws = (float*)d_ws;
    size_t off = 0;
    auto alloc = [&](size_t n) { float* p = ws + off; off += n; return p; };
    float* Xp    = alloc((size_t)TB * 128);
    float* Xw    = alloc((size_t)TB * 512);
    float* Ap    = alloc((size_t)TB * 1024);       // Wih_emb@p_emb + p biases
    float* Hp    = alloc((size_t)(TB + B) * 256);  // slot t+1 = h_p(t); slot 0 = zeros
    float* Hw1   = alloc((size_t)(TB + B) * 1024); // slot t+1 = h_w1(t); slot 0 = zeros
    float* E     = alloc((size_t)TB * 512);
    float* c_p   = alloc((size_t)B * 256);
    float* h_w0  = alloc((size_t)B * 1024);
    float* c_w0  = alloc((size_t)B * 1024);
    float* c_w1  = alloc((size_t)B * 1024);
    float* u     = alloc((size_t)B * 1024);
    float* v     = alloc((size_t)B * 256);
    float* hp_hh = alloc((size_t)B * 1024);
    float* w0_hh = alloc((size_t)B * 4096);
    float* w1_hh = alloc((size_t)B * 4096);
    unsigned* flags = (unsigned*)alloc(512);       // 64 steps x 8 flag counters

    // big A_w precompute parked in the (not-yet-written) w_out region of d_out
    float* Aw = Wout;  // [2048 x 4096] — dead before phase-2 logits overwrite it

    // zero initial states (c_p,h_w0,c_w0,c_w1 are contiguous) + flag counters
    hipMemsetAsync(c_p, 0, (size_t)(B * 256 + 3 * B * 1024) * 4, stream);
    hipMemsetAsync(Hp,  0, (size_t)B * 256 * 4, stream);
    hipMemsetAsync(Hw1, 0, (size_t)B * 1024 * 4, stream);
    hipMemsetAsync(flags, 0, 512 * 4, stream);

    // phase 0: embeddings + input-projection precomputes (biases folded in)
    gather_emb<<<TB, 128, 0, stream>>>(pos, word, pos_emb_W, word_emb_W, Xp, Xw);
    gemm_generic<<<dim3(16, 64), 128, 0, stream>>>(Xp, 128, p_Wih0, 1152,
        p_bih0, p_bhh0, Ap, 1024, 1024, 128, 0, 0);
    gemm_generic<<<dim3(64, 64), 128, 0, stream>>>(Xw, 512, w_Wih0, 768,
        w_bih0, w_bhh0, Aw, 4096, 4096, 512, 0, 0);

    // phase 1: register-resident persistent recurrence (one launch)
    RecArgs ra;
    ra.w2p_W = w2p_W; ra.w2p_b = w2p_b; ra.p_Whh0 = p_Whh0;
    ra.p2w_W = p2w_W; ra.p2w_b = p2w_b;
    ra.p_Wih0 = p_Wih0; ra.w_Wih0 = w_Wih0; ra.w_Wih1 = w_Wih1;
    ra.w_Whh0 = w_Whh0; ra.w_Whh1 = w_Whh1; ra.w_bih1 = w_bih1; ra.w_bhh1 = w_bhh1;
    ra.Ap = Ap; ra.Aw = Aw;
    ra.u = u; ra.v = v; ra.hp_hh = hp_hh; ra.w0_hh = w0_hh; ra.w1_hh = w1_hh;
    ra.Hp = Hp; ra.Hw1 = Hw1; ra.h_w0 = h_w0;
    ra.c_p = c_p; ra.c_w0 = c_w0; ra.c_w1 = c_w1;
    ra.flags = flags;
    recurrence_rr<<<248, 256, 0, stream>>>(ra);

    // phase 2: batched heads
    gemm_generic<<<dim3(8, 64), 128, 0, stream>>>(Hw1 + 32 * 1024, 1024,
        word_proj1W, 1024, word_proj1b, nullptr, E, 512, 512, 1024, 0, 0);
    gemm_generic<<<dim3(64, 500), 128, 0, stream>>>(E, 512, word_emb_W, 512,
        word_proj2b, nullptr, Wout, 32000, 32000, 512, 0, 1);
    logsoftmax_w<<<TB, 256, 0, stream>>>(Wout);
    pos_out_k<<<TB / 4, 256, 0, stream>>>(Hp + 32 * 256, pos_proj_W, pos_proj_b, Pout);
}